// Round 8
// baseline (502.207 us; speedup 1.0000x reference)
//
#include <hip/hip_runtime.h>
#include <hip/hip_fp16.h>

typedef unsigned int u32;

#define OUTD  4096
#define BATCH 4096
#define DEXC  8192
#define DINH  2048
#define KEXC  32
#define KINH  16
#define NB    2                            // batches per group (u32 per j in LDS)
#define NGRP  2                            // groups per block (ping-pong)
#define BUF_BYTES (DEXC * 4 + DINH * 4)    // 40960 B per buffer
#define LDS_BYTES (BUF_BYTES * 2)          // 81920 B -> 2 blocks/CU
constexpr int CAP = 1024;

// ---------------- fused top-k + exp + pack ----------------
// Emits (fp16(exp(w))<<16)|(idx*4) in k-major-interleaved layout:
// dword index ((r>>2)*OUTD+o)*4+(r&3) -> main loads uint4 at kk*OUTD+o.
// Low 16 bits are the LDS BYTE offset (j*4, j<8192 -> fits 16 bits).
template<int IN, int K>
__device__ __forceinline__ void topk_row(const float* __restrict__ pw, u32* __restrict__ pack_out,
                                         int o, float T0,
                                         float* s_val, int* s_idx, int* s_red, int* s_misc) {
  constexpr int V4 = IN / 1024;            // float4 per thread
  const int tid = threadIdx.x;
  const float4* row = (const float4*)(pw + (size_t)o * IN);

  float4 v[V4];
#pragma unroll
  for (int c = 0; c < V4; ++c) v[c] = row[tid + c * 256];

  // threshold search: K <= count(>T) <= CAP (T0 statistically right ~99.5% of rows)
  float T = T0;
  int C = 0;
  for (int iter = 0; iter < 50; ++iter) {
    int cnt = 0;
#pragma unroll
    for (int c = 0; c < V4; ++c)
      cnt += (v[c].x > T) + (v[c].y > T) + (v[c].z > T) + (v[c].w > T);
#pragma unroll
    for (int off = 32; off >= 1; off >>= 1) cnt += __shfl_down(cnt, off, 64);
    if ((tid & 63) == 0) s_red[tid >> 6] = cnt;
    __syncthreads();
    if (tid == 0) s_misc[0] = s_red[0] + s_red[1] + s_red[2] + s_red[3];
    __syncthreads();
    C = s_misc[0];
    if (C >= K && C <= CAP) break;
    if (iter >= 47)    T = -1e30f;
    else if (C < K)    T -= 0.75f;
    else               T += 0.375f;
    __syncthreads();
  }

  if (tid == 0) s_misc[1] = 0;
  __syncthreads();
#pragma unroll
  for (int c = 0; c < V4; ++c) {
    const float vv[4] = {v[c].x, v[c].y, v[c].z, v[c].w};
#pragma unroll
    for (int q = 0; q < 4; ++q) {
      if (vv[q] > T) {
        int p = atomicAdd(&s_misc[1], 1);
        if (p < CAP) { s_val[p] = vv[q]; s_idx[p] = (tid + c * 256) * 4 + q; }
      }
    }
  }
  __syncthreads();
  C = s_misc[1] < CAP ? s_misc[1] : CAP;

  // O(C^2) rank select (C ~ 50); tie-break by lower index; ranks are a bijection.
  for (int t = tid; t < C; t += 256) {
    const float mv = s_val[t];
    const int   mi = s_idx[t];
    int r = 0;
    for (int q = 0; q < C; ++q) {
      const float qv = s_val[q];
      r += ((qv > mv) || (qv == mv && s_idx[q] < mi)) ? 1 : 0;
    }
    if (r < K) {
      const float w = __expf(mv);
      const u32 hb = (u32)__half_as_ushort(__float2half(w));
      pack_out[((r >> 2) * OUTD + o) * 4 + (r & 3)] = (hb << 16) | ((u32)mi << 2);
    }
  }
}

__global__ __launch_bounds__(256)
void topk_both(const float* __restrict__ pwe, const float* __restrict__ pwi,
               u32* __restrict__ packE, u32* __restrict__ packI) {
  __shared__ float s_val[CAP];
  __shared__ int   s_idx[CAP];
  __shared__ int   s_red[4];
  __shared__ int   s_misc[2];
  if (blockIdx.x < OUTD)
    topk_row<DEXC, KEXC>(pwe, packE, blockIdx.x, 2.5f, s_val, s_idx, s_red, s_misc);
  else
    topk_row<DINH, KINH>(pwi, packI, blockIdx.x - OUTD, 2.0f, s_val, s_idx, s_red, s_misc);
}

// ---------------- main gather kernel ----------------
__device__ __forceinline__ u32 pack2f(float a, float b) {
  __half2 h = __floats2half2_rn(a, b);
  return __builtin_bit_cast(u32, h);
}

// u = (fp16 w << 16) | byte_offset. One ds_read_b32 = x[j][b0,b1] fp16 pair.
__device__ __forceinline__ void accum1(u32 u, const char* __restrict__ ldsBase, __half2& acc) {
  const u32 jb = u & 0xFFFFu;
  const u32 wb = __builtin_amdgcn_perm(u, u, 0x03020302u);  // {w,w} fp16 pair
  const __half2 w2 = __builtin_bit_cast(__half2, wb);
  const u32 xf = *(const u32*)(ldsBase + jb);               // ds_read_b32
  acc = __hfma2(w2, __builtin_bit_cast(__half2, xf), acc);
}

__device__ __forceinline__ void gatherR(const uint4* __restrict__ pe4, const uint4* __restrict__ pi4,
                                        const char* __restrict__ Ec, const char* __restrict__ Ic,
                                        int o, __half2& e, __half2& ia) {
  const __half2 z = __builtin_bit_cast(__half2, 0u);
  e = z; ia = z;
#pragma unroll
  for (int kk = 0; kk < KEXC / 4; ++kk) {
    const uint4 p = pe4[kk * OUTD + o];    // coalesced 16 B/lane, L2-resident
    accum1(p.x, Ec, e); accum1(p.y, Ec, e);
    accum1(p.z, Ec, e); accum1(p.w, Ec, e);
  }
#pragma unroll
  for (int kk = 0; kk < KINH / 4; ++kk) {
    const uint4 p = pi4[kk * OUTD + o];
    accum1(p.x, Ic, ia); accum1(p.y, Ic, ia);
    accum1(p.z, Ic, ia); accum1(p.w, Ic, ia);
  }
}

__device__ __forceinline__ void writeOut(float* __restrict__ out, int b0, int o,
                                         __half2 e, __half2 ia) {
  const float2 ev = __half22float2(e);
  const float2 iv = __half22float2(ia);
  out[(size_t)b0 * OUTD + o]       = ev.x * __builtin_amdgcn_rcpf(1.0f + iv.x);
  out[(size_t)(b0 + 1) * OUTD + o] = ev.y * __builtin_amdgcn_rcpf(1.0f + iv.y);
}

__global__ __launch_bounds__(1024, 8)
void dendrite_main(const float* __restrict__ xe, const float* __restrict__ xi,
                   const uint4* __restrict__ pe4, const uint4* __restrict__ pi4,
                   float* __restrict__ out) {
  extern __shared__ char smem[];
  u32* E0 = (u32*)smem;                              // [DEXC] 32 KiB
  u32* I0 = (u32*)(smem + DEXC * 4);                 // [DINH]  8 KiB
  u32* E1 = (u32*)(smem + BUF_BYTES);
  u32* I1 = (u32*)(smem + BUF_BYTES + DEXC * 4);
  const char* E0c = (const char*)E0;  const char* I0c = (const char*)I0;
  const char* E1c = (const char*)E1;  const char* I1c = (const char*)I1;
  const int tid  = threadIdx.x;
  const int base = blockIdx.x * (NB * NGRP);         // 4 batch rows per block

  // ---- stage group 0 -> buf0 (exposed once) ----
  {
    const float4 a0 = ((const float4*)(xe + (size_t)(base + 0) * DEXC))[tid];
    const float4 a1 = ((const float4*)(xe + (size_t)(base + 1) * DEXC))[tid];
    u32* d = E0 + tid * 4;
    d[0] = pack2f(a0.x, a1.x); d[1] = pack2f(a0.y, a1.y);
    d[2] = pack2f(a0.z, a1.z); d[3] = pack2f(a0.w, a1.w);
    const float4 b0v = ((const float4*)(xe + (size_t)(base + 0) * DEXC))[tid + 1024];
    const float4 b1v = ((const float4*)(xe + (size_t)(base + 1) * DEXC))[tid + 1024];
    u32* d2 = E0 + (tid + 1024) * 4;
    d2[0] = pack2f(b0v.x, b1v.x); d2[1] = pack2f(b0v.y, b1v.y);
    d2[2] = pack2f(b0v.z, b1v.z); d2[3] = pack2f(b0v.w, b1v.w);
    if (tid < DINH / 4) {
      const float4 c0 = ((const float4*)(xi + (size_t)(base + 0) * DINH))[tid];
      const float4 c1 = ((const float4*)(xi + (size_t)(base + 1) * DINH))[tid];
      u32* d3 = I0 + tid * 4;
      d3[0] = pack2f(c0.x, c1.x); d3[1] = pack2f(c0.y, c1.y);
      d3[2] = pack2f(c0.z, c1.z); d3[3] = pack2f(c0.w, c1.w);
    }
  }
  __syncthreads();

  // ---- phase A: gather group 0 from buf0, stage group 1 -> buf1 interleaved
  //      (each staged load issued one gather earlier than its LDS write, so
  //      HBM latency hides under ~6000 cy of gather work; <=8 live stage regs) ----
  {
    const int b0 = base;
    __half2 e, ia;

    const float4 a0 = ((const float4*)(xe + (size_t)(base + 2) * DEXC))[tid];
    const float4 a1 = ((const float4*)(xe + (size_t)(base + 3) * DEXC))[tid];
    gatherR(pe4, pi4, E0c, I0c, tid, e, ia);
    writeOut(out, b0, tid, e, ia);
    { u32* d = E1 + tid * 4;
      d[0] = pack2f(a0.x, a1.x); d[1] = pack2f(a0.y, a1.y);
      d[2] = pack2f(a0.z, a1.z); d[3] = pack2f(a0.w, a1.w); }

    const float4 b0v = ((const float4*)(xe + (size_t)(base + 2) * DEXC))[tid + 1024];
    const float4 b1v = ((const float4*)(xe + (size_t)(base + 3) * DEXC))[tid + 1024];
    gatherR(pe4, pi4, E0c, I0c, tid + 1024, e, ia);
    writeOut(out, b0, tid + 1024, e, ia);
    { u32* d = E1 + (tid + 1024) * 4;
      d[0] = pack2f(b0v.x, b1v.x); d[1] = pack2f(b0v.y, b1v.y);
      d[2] = pack2f(b0v.z, b1v.z); d[3] = pack2f(b0v.w, b1v.w); }

    float4 c0, c1;
    if (tid < DINH / 4) {
      c0 = ((const float4*)(xi + (size_t)(base + 2) * DINH))[tid];
      c1 = ((const float4*)(xi + (size_t)(base + 3) * DINH))[tid];
    }
    gatherR(pe4, pi4, E0c, I0c, tid + 2048, e, ia);
    writeOut(out, b0, tid + 2048, e, ia);
    if (tid < DINH / 4) {
      u32* d = I1 + tid * 4;
      d[0] = pack2f(c0.x, c1.x); d[1] = pack2f(c0.y, c1.y);
      d[2] = pack2f(c0.z, c1.z); d[3] = pack2f(c0.w, c1.w);
    }

    gatherR(pe4, pi4, E0c, I0c, tid + 3072, e, ia);
    writeOut(out, b0, tid + 3072, e, ia);
  }
  __syncthreads();

  // ---- phase B: gather group 1 from buf1 (no staging) ----
  {
    const int b0 = base + 2;
    __half2 e, ia;
#pragma unroll
    for (int r = 0; r < 4; ++r) {
      const int o = tid + r * 1024;
      gatherR(pe4, pi4, E1c, I1c, o, e, ia);
      writeOut(out, b0, o, e, ia);
    }
  }
}

extern "C" void kernel_launch(void* const* d_in, const int* in_sizes, int n_in,
                              void* d_out, int out_size, void* d_ws, size_t ws_size,
                              hipStream_t stream) {
  const float* xe  = (const float*)d_in[0];   // x_exc  [4096][8192]
  const float* xi  = (const float*)d_in[1];   // x_inh  [4096][2048]
  const float* pwe = (const float*)d_in[2];   // pre_w_exc [4096][8192]
  const float* pwi = (const float*)d_in[3];   // pre_w_inh [4096][2048]
  u32* packE = (u32*)d_ws;                    // OUTD*KEXC u32 = 512 KiB
  u32* packI = packE + OUTD * KEXC;           // OUTD*KINH u32 = 256 KiB

  (void)hipFuncSetAttribute((const void*)dendrite_main,
                            hipFuncAttributeMaxDynamicSharedMemorySize, LDS_BYTES);

  topk_both<<<2 * OUTD, 256, 0, stream>>>(pwe, pwi, packE, packI);
  dendrite_main<<<BATCH / (NB * NGRP), 1024, LDS_BYTES, stream>>>(
      xe, xi, (const uint4*)packE, (const uint4*)packI, (float*)d_out);
}

// Round 9
// 366.418 us; speedup vs baseline: 1.3706x; 1.3706x over previous
//
#include <hip/hip_runtime.h>
#include <hip/hip_fp16.h>

typedef unsigned int u32;

#define OUTD  4096
#define BATCH 4096
#define DEXC  8192
#define DINH  2048
#define KEXC  32
#define KINH  16
#define NB    4
#define LDS_BYTES (DEXC * 8 + DINH * 8)   // 65536 + 16384 = 81920 B -> 2 blocks/CU
constexpr int CAP = 1024;

// ---------------- fused top-k + exp + pack ----------------
// One block per output row (exc rows then inh rows in one grid so the two
// problems overlap). Emits (fp16(exp(w))<<16)|(idx*8) in k-major-interleaved
// layout: dword index ((r>>2)*OUTD+o)*4+(r&3) -> main loads uint4 at kk*OUTD+o.
// Low 16 bits are the LDS BYTE offset (j*8, j<8192 -> fits 16 bits).
template<int IN, int K>
__device__ __forceinline__ void topk_row(const float* __restrict__ pw, u32* __restrict__ pack_out,
                                         int o, float T0,
                                         float* s_val, int* s_idx, int* s_red, int* s_misc) {
  constexpr int V4 = IN / 1024;            // float4 per thread
  const int tid = threadIdx.x;
  const float4* row = (const float4*)(pw + (size_t)o * IN);

  float4 v[V4];
#pragma unroll
  for (int c = 0; c < V4; ++c) v[c] = row[tid + c * 256];

  // threshold search: K <= count(>T) <= CAP (T0 statistically right ~99.5% of rows)
  float T = T0;
  int C = 0;
  for (int iter = 0; iter < 50; ++iter) {
    int cnt = 0;
#pragma unroll
    for (int c = 0; c < V4; ++c)
      cnt += (v[c].x > T) + (v[c].y > T) + (v[c].z > T) + (v[c].w > T);
#pragma unroll
    for (int off = 32; off >= 1; off >>= 1) cnt += __shfl_down(cnt, off, 64);
    if ((tid & 63) == 0) s_red[tid >> 6] = cnt;
    __syncthreads();
    if (tid == 0) s_misc[0] = s_red[0] + s_red[1] + s_red[2] + s_red[3];
    __syncthreads();
    C = s_misc[0];
    if (C >= K && C <= CAP) break;
    if (iter >= 47)    T = -1e30f;
    else if (C < K)    T -= 0.75f;
    else               T += 0.375f;
    __syncthreads();
  }

  if (tid == 0) s_misc[1] = 0;
  __syncthreads();
#pragma unroll
  for (int c = 0; c < V4; ++c) {
    const float vv[4] = {v[c].x, v[c].y, v[c].z, v[c].w};
#pragma unroll
    for (int q = 0; q < 4; ++q) {
      if (vv[q] > T) {
        int p = atomicAdd(&s_misc[1], 1);
        if (p < CAP) { s_val[p] = vv[q]; s_idx[p] = (tid + c * 256) * 4 + q; }
      }
    }
  }
  __syncthreads();
  C = s_misc[1] < CAP ? s_misc[1] : CAP;

  // O(C^2) rank select (C ~ 50); tie-break by lower index; ranks are a bijection.
  for (int t = tid; t < C; t += 256) {
    const float mv = s_val[t];
    const int   mi = s_idx[t];
    int r = 0;
    for (int q = 0; q < C; ++q) {
      const float qv = s_val[q];
      r += ((qv > mv) || (qv == mv && s_idx[q] < mi)) ? 1 : 0;
    }
    if (r < K) {
      const float w = __expf(mv);
      const u32 hb = (u32)__half_as_ushort(__float2half(w));
      pack_out[((r >> 2) * OUTD + o) * 4 + (r & 3)] = (hb << 16) | ((u32)mi << 3);
    }
  }
}

__global__ __launch_bounds__(256)
void topk_both(const float* __restrict__ pwe, const float* __restrict__ pwi,
               u32* __restrict__ packE, u32* __restrict__ packI) {
  __shared__ float s_val[CAP];
  __shared__ int   s_idx[CAP];
  __shared__ int   s_red[4];
  __shared__ int   s_misc[2];
  if (blockIdx.x < OUTD)
    topk_row<DEXC, KEXC>(pwe, packE, blockIdx.x, 2.5f, s_val, s_idx, s_red, s_misc);
  else
    topk_row<DINH, KINH>(pwi, packI, blockIdx.x - OUTD, 2.0f, s_val, s_idx, s_red, s_misc);
}

// ---------------- main gather kernel ----------------
__device__ __forceinline__ u32 pack2f(float a, float b) {
  __half2 h = __floats2half2_rn(a, b);
  return __builtin_bit_cast(u32, h);
}

// u = (fp16 w << 16) | byte_offset. Low 16 bits index LDS directly (no shift).
__device__ __forceinline__ void accum2(u32 u, const char* __restrict__ ldsBase, __half2 acc[2]) {
  const u32 jb = u & 0xFFFFu;
  const u32 wb = __builtin_amdgcn_perm(u, u, 0x03020302u);  // {w,w} fp16 pair
  const __half2 w2 = __builtin_bit_cast(__half2, wb);
  const uint2 xf = *(const uint2*)(ldsBase + jb);           // ds_read_b64: x[j][b0..b3] fp16
  acc[0] = __hfma2(w2, __builtin_bit_cast(__half2, xf.x), acc[0]);
  acc[1] = __hfma2(w2, __builtin_bit_cast(__half2, xf.y), acc[1]);
}

__global__ __launch_bounds__(1024, 8)
void dendrite_main(const float* __restrict__ xe, const float* __restrict__ xi,
                   const uint4* __restrict__ pe4, const uint4* __restrict__ pi4,
                   float* __restrict__ out) {
  extern __shared__ char smem[];
  uint2* ldsE = (uint2*)smem;                  // [DEXC] : x_exc[j][b0..b3] fp16, 64 KiB
  uint2* ldsI = (uint2*)(smem + DEXC * 8);     // [DINH] : 16 KiB
  const char* ldsEc = (const char*)smem;
  const char* ldsIc = (const char*)(smem + DEXC * 8);
  const int tid = threadIdx.x;
  const int b0  = blockIdx.x * NB;

  // ---- stage 4 batch rows, f32 -> fp16, transposed [j][b], float4 loads ----
  // (runs at wave priority 0: a co-resident block in its gather phase wins
  //  issue slots; this block's stage fills that block's stall bubbles)
#pragma unroll
  for (int it = 0; it < DEXC / 4096; ++it) {   // 2 iters, 4 j per thread
    const int j4 = tid + it * 1024;
    float4 r0 = ((const float4*)(xe + (size_t)(b0 + 0) * DEXC))[j4];
    float4 r1 = ((const float4*)(xe + (size_t)(b0 + 1) * DEXC))[j4];
    float4 r2 = ((const float4*)(xe + (size_t)(b0 + 2) * DEXC))[j4];
    float4 r3 = ((const float4*)(xe + (size_t)(b0 + 3) * DEXC))[j4];
    uint2* dst = ldsE + j4 * 4;
    dst[0] = {pack2f(r0.x, r1.x), pack2f(r2.x, r3.x)};
    dst[1] = {pack2f(r0.y, r1.y), pack2f(r2.y, r3.y)};
    dst[2] = {pack2f(r0.z, r1.z), pack2f(r2.z, r3.z)};
    dst[3] = {pack2f(r0.w, r1.w), pack2f(r2.w, r3.w)};
  }
  if (tid < DINH / 4) {                        // 512 threads, 1 iter
    const int j4 = tid;
    float4 r0 = ((const float4*)(xi + (size_t)(b0 + 0) * DINH))[j4];
    float4 r1 = ((const float4*)(xi + (size_t)(b0 + 1) * DINH))[j4];
    float4 r2 = ((const float4*)(xi + (size_t)(b0 + 2) * DINH))[j4];
    float4 r3 = ((const float4*)(xi + (size_t)(b0 + 3) * DINH))[j4];
    uint2* dst = ldsI + j4 * 4;
    dst[0] = {pack2f(r0.x, r1.x), pack2f(r2.x, r3.x)};
    dst[1] = {pack2f(r0.y, r1.y), pack2f(r2.y, r3.y)};
    dst[2] = {pack2f(r0.z, r1.z), pack2f(r2.z, r3.z)};
    dst[3] = {pack2f(r0.w, r1.w), pack2f(r2.w, r3.w)};
  }
  __syncthreads();

  // ---- gather at wave priority 1: prefer gather issue over the co-resident
  //      block's stage phase (independent blocks -> m191-positive regime) ----
  __builtin_amdgcn_s_setprio(1);
#pragma unroll
  for (int r = 0; r < OUTD / 1024; ++r) {
    const int o = tid + r * 1024;
    const __half2 z = __builtin_bit_cast(__half2, 0u);
    __half2 e[2]  = {z, z};
    __half2 ia[2] = {z, z};
#pragma unroll
    for (int kk = 0; kk < KEXC / 4; ++kk) {
      const uint4 p = pe4[kk * OUTD + o];      // coalesced 16 B/lane, L2-resident
      accum2(p.x, ldsEc, e); accum2(p.y, ldsEc, e);
      accum2(p.z, ldsEc, e); accum2(p.w, ldsEc, e);
    }
#pragma unroll
    for (int kk = 0; kk < KINH / 4; ++kk) {
      const uint4 p = pi4[kk * OUTD + o];
      accum2(p.x, ldsIc, ia); accum2(p.y, ldsIc, ia);
      accum2(p.z, ldsIc, ia); accum2(p.w, ldsIc, ia);
    }
#pragma unroll
    for (int d = 0; d < 2; ++d) {
      const float2 ev = __half22float2(e[d]);
      const float2 iv = __half22float2(ia[d]);
      out[(size_t)(b0 + 2 * d    ) * OUTD + o] = ev.x * __builtin_amdgcn_rcpf(1.0f + iv.x);
      out[(size_t)(b0 + 2 * d + 1) * OUTD + o] = ev.y * __builtin_amdgcn_rcpf(1.0f + iv.y);
    }
  }
  __builtin_amdgcn_s_setprio(0);
}

extern "C" void kernel_launch(void* const* d_in, const int* in_sizes, int n_in,
                              void* d_out, int out_size, void* d_ws, size_t ws_size,
                              hipStream_t stream) {
  const float* xe  = (const float*)d_in[0];   // x_exc  [4096][8192]
  const float* xi  = (const float*)d_in[1];   // x_inh  [4096][2048]
  const float* pwe = (const float*)d_in[2];   // pre_w_exc [4096][8192]
  const float* pwi = (const float*)d_in[3];   // pre_w_inh [4096][2048]
  u32* packE = (u32*)d_ws;                    // OUTD*KEXC u32 = 512 KiB
  u32* packI = packE + OUTD * KEXC;           // OUTD*KINH u32 = 256 KiB

  (void)hipFuncSetAttribute((const void*)dendrite_main,
                            hipFuncAttributeMaxDynamicSharedMemorySize, LDS_BYTES);

  topk_both<<<2 * OUTD, 256, 0, stream>>>(pwe, pwi, packE, packI);
  dendrite_main<<<BATCH / NB, 1024, LDS_BYTES, stream>>>(
      xe, xi, (const uint4*)packE, (const uint4*)packI, (float*)d_out);
}